// Round 1
// baseline (657.099 us; speedup 1.0000x reference)
//
#include <hip/hip_runtime.h>
#include <hip/hip_bf16.h>
#include <stdint.h>
#include <stddef.h>

// Problem constants (B=4, S=2048, D_IN=D_OUT=4096, r=16, scaling/r = 1.0)
#define D_IN   4096
#define D_OUT  4096
#define M_TOT  8192
#define R_RANK 16
#define RP     32          // rank padded to one K=32 MFMA step
#define LORA_SCALE 1.0f    // SCALING / R = 16/16

typedef __attribute__((ext_vector_type(8))) short short8;   // 8 x bf16 (4 VGPRs)
typedef __attribute__((ext_vector_type(4))) float f32x4;    // MFMA accumulator

// async global->LDS, 16B per lane. LDS dest must be wave-uniform base + lane*16.
#define GL2LDS16(g, l)                                                  \
  __builtin_amdgcn_global_load_lds(                                     \
      (const __attribute__((address_space(1))) void*)(g),               \
      (__attribute__((address_space(3))) void*)(l), 16, 0, 0)

// ---------------------------------------------------------------------------
// prep_ab: Asb[i][r] = bf16(A[r][i] * c[r] * LORA_SCALE)  (r-major, padded to 32)
//          Bbb[o][r] = bf16(B[o][r])                      (r-major, padded to 32)
// ---------------------------------------------------------------------------
__global__ __launch_bounds__(256) void prep_ab(
    const float* __restrict__ A, const float* __restrict__ c,
    const float* __restrict__ B,
    __hip_bfloat16* __restrict__ Asb, __hip_bfloat16* __restrict__ Bbb) {
  int i = blockIdx.x * 256 + threadIdx.x;  // 0..4095 (D_IN == D_OUT)
  if (i >= D_IN) return;
  float cs[R_RANK];
#pragma unroll
  for (int r = 0; r < R_RANK; r++) cs[r] = c[r] * LORA_SCALE;
#pragma unroll
  for (int r = 0; r < R_RANK; r++) {
    Asb[i * RP + r] = __float2bfloat16(A[r * D_IN + i] * cs[r]);
    Bbb[i * RP + r] = __float2bfloat16(B[i * R_RANK + r]);
  }
#pragma unroll
  for (int r = R_RANK; r < RP; r++) {
    Asb[i * RP + r] = __float2bfloat16(0.0f);
    Bbb[i * RP + r] = __float2bfloat16(0.0f);
  }
}

// ---------------------------------------------------------------------------
// prep_w: Wp[o][i] = bf16( W[o][i] + sum_r Bbb[o][r] * Asb[i][r] )
// One 16x16 tile per wave via a single 16x16x32 bf16 MFMA (K = RP = 32).
// ---------------------------------------------------------------------------
__global__ __launch_bounds__(256) void prep_w(
    const float* __restrict__ W,
    const __hip_bfloat16* __restrict__ Asb,
    const __hip_bfloat16* __restrict__ Bbb,
    __hip_bfloat16* __restrict__ Wp) {
  int wid  = threadIdx.x >> 6;
  int lane = threadIdx.x & 63;
  int tile = blockIdx.x * 4 + wid;       // 0..65535
  int ti = (tile & 255) * 16;            // i-tile (fast → coalesced-ish stores)
  int to = (tile >> 8) * 16;             // o-tile
  int l15 = lane & 15;
  int kg  = lane >> 4;                   // 0..3

  // A-operand = Bbb rows (m = o), B-operand = Asb rows (n = i); lane layout:
  // m/n = lane&15, k = (lane>>4)*8 + j  → one contiguous 16B read per lane.
  short8 a = *(const short8*)(Bbb + (size_t)(to + l15) * RP + kg * 8);
  short8 b = *(const short8*)(Asb + (size_t)(ti + l15) * RP + kg * 8);
  f32x4 d = {0.f, 0.f, 0.f, 0.f};
  d = __builtin_amdgcn_mfma_f32_16x16x32_bf16(a, b, d, 0, 0, 0);

  // C/D layout: col(n=i) = lane&15, row(m=o) = (lane>>4)*4 + reg
#pragma unroll
  for (int reg = 0; reg < 4; reg++) {
    int o = to + kg * 4 + reg;
    int i = ti + l15;
    float v = W[(size_t)o * D_IN + i] + d[reg];
    Wp[(size_t)o * D_IN + i] = __float2bfloat16(v);
  }
}

// ---------------------------------------------------------------------------
// pack_x: fp32 -> bf16, 8 elements/thread, 16B stores
// ---------------------------------------------------------------------------
__global__ __launch_bounds__(256) void pack_x(
    const float* __restrict__ x, __hip_bfloat16* __restrict__ Xp) {
  size_t idx = ((size_t)blockIdx.x * 256 + threadIdx.x) * 8;
  float4 v0 = *(const float4*)(x + idx);
  float4 v1 = *(const float4*)(x + idx + 4);
  __hip_bfloat16 t[8];
  t[0] = __float2bfloat16(v0.x); t[1] = __float2bfloat16(v0.y);
  t[2] = __float2bfloat16(v0.z); t[3] = __float2bfloat16(v0.w);
  t[4] = __float2bfloat16(v1.x); t[5] = __float2bfloat16(v1.y);
  t[6] = __float2bfloat16(v1.z); t[7] = __float2bfloat16(v1.w);
  *(short8*)(Xp + idx) = *(const short8*)t;
}

// ---------------------------------------------------------------------------
// gemm_main: out[m][n] = sum_k Xp[m][k]*Wp[n][k] + bias[n]   (fp32 out)
// m97 structure: 128x128 tile, BK=64, 256 threads = 2x2 waves of 64x64,
// global_load_lds width-16 staging, 16x16x32 bf16 MFMA, fp32 epilogue.
// ---------------------------------------------------------------------------
#define BM 128
#define BN 128
#define BK 64

__global__ __launch_bounds__(256) void gemm_main(
    const __hip_bfloat16* __restrict__ Xp,
    const __hip_bfloat16* __restrict__ Wp,
    const float* __restrict__ bias,
    float* __restrict__ out) {
  __shared__ __align__(16) __hip_bfloat16 As[BM * BK];  // [128][64], k-contig
  __shared__ __align__(16) __hip_bfloat16 Bs[BN * BK];  // [128][64], k-contig

  int tid  = threadIdx.x;
  int wid  = tid >> 6;
  int lane = tid & 63;
  int wm = wid >> 1, wn = wid & 1;      // 2x2 wave grid
  int m0 = blockIdx.y * BM;
  int n0 = blockIdx.x * BN;
  int l15 = lane & 15;
  int kg  = lane >> 4;                  // 0..3

  // staging: each wave-issue deposits 1024 contiguous LDS bytes = 8 rows x 64 bf16
  int srow = lane >> 3;                 // 0..7
  int scol = (lane & 7) * 8;            // bf16 col, 16B per lane

  f32x4 acc[4][4];
#pragma unroll
  for (int i = 0; i < 4; i++)
#pragma unroll
    for (int j = 0; j < 4; j++) acc[i][j] = (f32x4){0.f, 0.f, 0.f, 0.f};

  for (int kt = 0; kt < D_IN; kt += BK) {
    __syncthreads();  // previous compute done before overwriting LDS
#pragma unroll
    for (int j = 0; j < 4; j++) {
      int row = wid * 32 + j * 8 + srow;          // 0..127 across waves+issues
      const __hip_bfloat16* ga = Xp + (size_t)(m0 + row) * D_IN + kt + scol;
      GL2LDS16(ga, As + row * BK + scol);
      const __hip_bfloat16* gb = Wp + (size_t)(n0 + row) * D_IN + kt + scol;
      GL2LDS16(gb, Bs + row * BK + scol);
    }
    __syncthreads();  // drains vmcnt: staged tile visible

#pragma unroll
    for (int kk = 0; kk < BK; kk += 32) {
      short8 af[4], bb[4];
#pragma unroll
      for (int am = 0; am < 4; am++)
        af[am] = *(const short8*)(As + (wm * 64 + am * 16 + l15) * BK + kk + kg * 8);
#pragma unroll
      for (int bn = 0; bn < 4; bn++)
        bb[bn] = *(const short8*)(Bs + (wn * 64 + bn * 16 + l15) * BK + kk + kg * 8);
#pragma unroll
      for (int am = 0; am < 4; am++)
#pragma unroll
        for (int bn = 0; bn < 4; bn++)
          acc[am][bn] = __builtin_amdgcn_mfma_f32_16x16x32_bf16(
              af[am], bb[bn], acc[am][bn], 0, 0, 0);
    }
  }

  // epilogue: C/D layout col = lane&15 (n), row = (lane>>4)*4+reg (m); + bias
  float bv[4];
#pragma unroll
  for (int bn = 0; bn < 4; bn++) bv[bn] = bias[n0 + wn * 64 + bn * 16 + l15];
#pragma unroll
  for (int am = 0; am < 4; am++) {
#pragma unroll
    for (int reg = 0; reg < 4; reg++) {
      int row = m0 + wm * 64 + am * 16 + kg * 4 + reg;
      float* po = out + (size_t)row * D_OUT + n0 + wn * 64 + l15;
#pragma unroll
      for (int bn = 0; bn < 4; bn++) po[bn * 16] = acc[am][bn][reg] + bv[bn];
    }
  }
}

// ---------------------------------------------------------------------------
extern "C" void kernel_launch(void* const* d_in, const int* in_sizes, int n_in,
                              void* d_out, int out_size, void* d_ws, size_t ws_size,
                              hipStream_t stream) {
  const float* x  = (const float*)d_in[0];   // [4,2048,4096]
  const float* W  = (const float*)d_in[1];   // [4096,4096]
  const float* b  = (const float*)d_in[2];   // [4096]
  const float* lA = (const float*)d_in[3];   // [16,4096]
  const float* lB = (const float*)d_in[4];   // [4096,16]
  const float* lc = (const float*)d_in[5];   // [16,1]
  float* out = (float*)d_out;                // [4,2048,4096] fp32

  char* ws = (char*)d_ws;
  __hip_bfloat16* Xp  = (__hip_bfloat16*)ws;                          // 64 MiB
  __hip_bfloat16* Wp  = (__hip_bfloat16*)(ws + (size_t)67108864);     // 32 MiB
  __hip_bfloat16* Asb = (__hip_bfloat16*)(ws + (size_t)100663296);    // 256 KiB
  __hip_bfloat16* Bbb = (__hip_bfloat16*)(ws + (size_t)100925440);    // 256 KiB

  prep_ab<<<dim3(16), dim3(256), 0, stream>>>(lA, lc, lB, Asb, Bbb);
  pack_x<<<dim3(M_TOT * D_IN / (256 * 8)), dim3(256), 0, stream>>>(x, Xp);
  prep_w<<<dim3(D_OUT * D_IN / (16 * 16 * 4)), dim3(256), 0, stream>>>(W, Asb, Bbb, Wp);
  gemm_main<<<dim3(D_OUT / BN, M_TOT / BM), dim3(256), 0, stream>>>(Xp, Wp, b, out);
}

// Round 2
// 599.826 us; speedup vs baseline: 1.0955x; 1.0955x over previous
//
#include <hip/hip_runtime.h>
#include <hip/hip_bf16.h>
#include <stdint.h>
#include <stddef.h>

// Problem constants (B=4, S=2048, D_IN=D_OUT=4096, r=16, scaling/r = 1.0)
#define D_IN   4096
#define D_OUT  4096
#define M_TOT  8192
#define R_RANK 16
#define LORA_SCALE 1.0f    // SCALING / R = 16/16

typedef __attribute__((ext_vector_type(8))) short short8;   // 8 x bf16 (4 VGPRs)
typedef __attribute__((ext_vector_type(4))) short short4v;  // 4 x bf16 (2 VGPRs)
typedef __attribute__((ext_vector_type(4))) float f32x4;    // MFMA accumulator

// async global->LDS, 16B per lane. LDS dest must be wave-uniform base + lane*16.
#define GL2LDS16(g, l)                                                  \
  __builtin_amdgcn_global_load_lds(                                     \
      (const __attribute__((address_space(1))) void*)(g),               \
      (__attribute__((address_space(3))) void*)(l), 16, 0, 0)

// ---------------------------------------------------------------------------
// prep_w: Wp[o][i] = bf16( W[o][i] + sum_r B[o][r]*c[r]*A[r][i] )  (VALU)
// grid (D_IN/1024, D_OUT/4), 256 thr. Thread: 4 consecutive i x 4 o-rows.
// A (256 KB) is L2-resident; A*c held in regs, reused across 4 o-rows.
// Fully coalesced float4 W loads, 8B bf16x4 stores.
// ---------------------------------------------------------------------------
__global__ __launch_bounds__(256) void prep_w(
    const float* __restrict__ W, const float* __restrict__ A,
    const float* __restrict__ c, const float* __restrict__ B,
    __hip_bfloat16* __restrict__ Wp) {
  int t  = threadIdx.x;
  int i  = blockIdx.x * 1024 + t * 4;
  int o0 = blockIdx.y * 4;

  float4 a4[R_RANK];
#pragma unroll
  for (int r = 0; r < R_RANK; r++) {
    float4 v = *(const float4*)(A + r * D_IN + i);
    float cr = c[r] * LORA_SCALE;
    v.x *= cr; v.y *= cr; v.z *= cr; v.w *= cr;
    a4[r] = v;
  }
#pragma unroll
  for (int oo = 0; oo < 4; oo++) {
    int o = o0 + oo;
    float4 w = *(const float4*)(W + (size_t)o * D_IN + i);
#pragma unroll
    for (int r = 0; r < R_RANK; r++) {
      float br = B[o * R_RANK + r];
      w.x += br * a4[r].x; w.y += br * a4[r].y;
      w.z += br * a4[r].z; w.w += br * a4[r].w;
    }
    __hip_bfloat16 tb[4];
    tb[0] = __float2bfloat16(w.x); tb[1] = __float2bfloat16(w.y);
    tb[2] = __float2bfloat16(w.z); tb[3] = __float2bfloat16(w.w);
    *(short4v*)(Wp + (size_t)o * D_IN + i) = *(const short4v*)tb;
  }
}

// ---------------------------------------------------------------------------
// pack_x: fp32 -> bf16, 8 elements/thread, 16B stores
// ---------------------------------------------------------------------------
__global__ __launch_bounds__(256) void pack_x(
    const float* __restrict__ x, __hip_bfloat16* __restrict__ Xp) {
  size_t idx = ((size_t)blockIdx.x * 256 + threadIdx.x) * 8;
  float4 v0 = *(const float4*)(x + idx);
  float4 v1 = *(const float4*)(x + idx + 4);
  __hip_bfloat16 t[8];
  t[0] = __float2bfloat16(v0.x); t[1] = __float2bfloat16(v0.y);
  t[2] = __float2bfloat16(v0.z); t[3] = __float2bfloat16(v0.w);
  t[4] = __float2bfloat16(v1.x); t[5] = __float2bfloat16(v1.y);
  t[6] = __float2bfloat16(v1.z); t[7] = __float2bfloat16(v1.w);
  *(short8*)(Xp + idx) = *(const short8*)t;
}

// ---------------------------------------------------------------------------
// gemm_main: out[m][n] = sum_k Xp[m][k]*Wp[n][k] + bias[n]   (fp32 out)
// m97 structure + XOR bank swizzle: logical colchunk c of row r lives at
// physical chunk c ^ (r&7). Deposit stays lane-contiguous (global_load_lds
// constraint); the permutation is applied to the GLOBAL source column.
// Readers XOR the chunk index with (row&7) -> 8 bank-quads, 2 lanes each
// (2-way = free, m136) instead of 16 lanes on one quad (16-way, ~5.7x).
// ---------------------------------------------------------------------------
#define BM 128
#define BN 128
#define BK 64

__global__ __launch_bounds__(256) void gemm_main(
    const __hip_bfloat16* __restrict__ Xp,
    const __hip_bfloat16* __restrict__ Wp,
    const float* __restrict__ bias,
    float* __restrict__ out) {
  __shared__ __align__(16) __hip_bfloat16 As[BM * BK];  // [128][64], swizzled
  __shared__ __align__(16) __hip_bfloat16 Bs[BN * BK];  // [128][64], swizzled

  int tid  = threadIdx.x;
  int wid  = tid >> 6;
  int lane = tid & 63;
  int wm = wid >> 1, wn = wid & 1;      // 2x2 wave grid
  int m0 = blockIdx.y * BM;
  int n0 = blockIdx.x * BN;
  int l15 = lane & 15;
  int kg  = lane >> 4;                  // 0..3
  int rx  = l15 & 7;                    // reader swizzle = row & 7

  // staging: wave-issue deposits 1024 contiguous LDS bytes = 8 rows x 8 chunks
  int srow  = lane >> 3;                          // 0..7 (= row & 7)
  int ldcol = (lane & 7) * 8;                     // physical LDS col (bf16)
  int gcol  = ((lane & 7) ^ srow) * 8;            // swizzled global col

  f32x4 acc[4][4];
#pragma unroll
  for (int i = 0; i < 4; i++)
#pragma unroll
    for (int j = 0; j < 4; j++) acc[i][j] = (f32x4){0.f, 0.f, 0.f, 0.f};

  for (int kt = 0; kt < D_IN; kt += BK) {
    __syncthreads();  // previous compute done before overwriting LDS
#pragma unroll
    for (int j = 0; j < 4; j++) {
      int row = wid * 32 + j * 8 + srow;          // 0..127 across waves+issues
      const __hip_bfloat16* ga = Xp + (size_t)(m0 + row) * D_IN + kt + gcol;
      GL2LDS16(ga, As + row * BK + ldcol);
      const __hip_bfloat16* gb = Wp + (size_t)(n0 + row) * D_IN + kt + gcol;
      GL2LDS16(gb, Bs + row * BK + ldcol);
    }
    __syncthreads();  // drains vmcnt: staged tile visible

#pragma unroll
    for (int kk = 0; kk < BK; kk += 32) {
      int ck = (kk >> 3) + kg;                    // logical chunk 0..7
      int pc = (ck ^ rx) * 8;                     // physical col (bf16)
      short8 af[4], bb[4];
#pragma unroll
      for (int am = 0; am < 4; am++)
        af[am] = *(const short8*)(As + (wm * 64 + am * 16 + l15) * BK + pc);
#pragma unroll
      for (int bn = 0; bn < 4; bn++)
        bb[bn] = *(const short8*)(Bs + (wn * 64 + bn * 16 + l15) * BK + pc);
#pragma unroll
      for (int am = 0; am < 4; am++)
#pragma unroll
        for (int bn = 0; bn < 4; bn++)
          acc[am][bn] = __builtin_amdgcn_mfma_f32_16x16x32_bf16(
              af[am], bb[bn], acc[am][bn], 0, 0, 0);
    }
  }

  // epilogue: C/D layout col = lane&15 (n), row = (lane>>4)*4+reg (m); + bias
  float bv[4];
#pragma unroll
  for (int bn = 0; bn < 4; bn++) bv[bn] = bias[n0 + wn * 64 + bn * 16 + l15];
#pragma unroll
  for (int am = 0; am < 4; am++) {
#pragma unroll
    for (int reg = 0; reg < 4; reg++) {
      int row = m0 + wm * 64 + am * 16 + kg * 4 + reg;
      float* po = out + (size_t)row * D_OUT + n0 + wn * 64 + l15;
#pragma unroll
      for (int bn = 0; bn < 4; bn++) po[bn * 16] = acc[am][bn][reg] + bv[bn];
    }
  }
}

// ---------------------------------------------------------------------------
extern "C" void kernel_launch(void* const* d_in, const int* in_sizes, int n_in,
                              void* d_out, int out_size, void* d_ws, size_t ws_size,
                              hipStream_t stream) {
  const float* x  = (const float*)d_in[0];   // [4,2048,4096]
  const float* W  = (const float*)d_in[1];   // [4096,4096]
  const float* b  = (const float*)d_in[2];   // [4096]
  const float* lA = (const float*)d_in[3];   // [16,4096]
  const float* lB = (const float*)d_in[4];   // [4096,16]
  const float* lc = (const float*)d_in[5];   // [16,1]
  float* out = (float*)d_out;                // [4,2048,4096] fp32

  char* ws = (char*)d_ws;
  __hip_bfloat16* Xp = (__hip_bfloat16*)ws;                       // 64 MiB
  __hip_bfloat16* Wp = (__hip_bfloat16*)(ws + (size_t)67108864);  // 32 MiB

  pack_x<<<dim3(M_TOT * D_IN / (256 * 8)), dim3(256), 0, stream>>>(x, Xp);
  prep_w<<<dim3(D_IN / 1024, D_OUT / 4), dim3(256), 0, stream>>>(W, lA, lc, lB, Wp);
  gemm_main<<<dim3(D_OUT / BN, M_TOT / BM), dim3(256), 0, stream>>>(Xp, Wp, b, out);
}